// Round 4
// baseline (434.669 us; speedup 1.0000x reference)
//
#include <hip/hip_runtime.h>
#include <math.h>

#define AR_P 48
#define FLEN 168
#define HISTLEN 336
#define TC 24            // t-chunk per block (168 = 7*24)

// ws layout (fp32): [0, 8064) W[t][k] t-major, [8064, 8232) ccm[t]
//   mu_orig[b,t] = ccm[t] + sum_k W[t,k]*y[b, 288+k]
//   ccm[t] = bias*(1+sum_{m<t} r_m[47])*sigma + mu - mu*sum_k W[t,k]

__global__ void k_coeffs(const float* __restrict__ phi,
                         const float* __restrict__ bias,
                         const float* __restrict__ mu_p,
                         const float* __restrict__ sigma_p,
                         float* __restrict__ ws) {
    const int k = threadIdx.x;  // 64 threads, 1 wave
    float* W   = ws;
    float* ccm = ws + AR_P * FLEN;
    const float mu     = mu_p[0];
    const float sigma  = sigma_p[0];
    const float bias_f = bias[0];
    const float phik = (k < AR_P) ? phi[k] : 0.0f;

    float r = phik;     // r_0 = phi; r_{t+1}[k] = r_t[k-1] + r_t[47]*phi[k]
    float csum = 0.0f;  // sum_{m<t} r_m[47]
    for (int t = 0; t < FLEN; ++t) {
        if (k < AR_P) W[t * AR_P + k] = r;
        // colsum = sum_k r_t[k] (lanes 48..63 hold 0) — butterfly
        float v = r;
#pragma unroll
        for (int off = 32; off > 0; off >>= 1) v += __shfl_xor(v, off, 64);
        if (k == 0)
            ccm[t] = bias_f * (1.0f + csum) * sigma + mu - mu * v;
        float r47 = __shfl(r, AR_P - 1, 64);
        csum += r47;
        float up = __shfl_up(r, 1, 64);
        float rn = (k == 0 ? 0.0f : up) + r47 * phik;
        r = (k < AR_P) ? rn : 0.0f;
    }
}

// Thread-per-row GEMM slice: block = 256 rows, grid.y picks a 24-wide t-chunk.
// W chunk lives in LDS; inner reads are wave-uniform -> broadcast (0 conflicts).
__global__ __launch_bounds__(256) void k_mu(
    const float* __restrict__ enc_l,
    const float* __restrict__ ws,
    const float* __restrict__ log_sigma2,
    const float* __restrict__ sigma_p,
    float* __restrict__ out,   // [B*168] mu, then [B*168] logvar
    int B) {
    __shared__ __align__(16) float lw[AR_P * TC];   // lw[k][j], row stride 24 (96 B)
    const int tid = threadIdx.x;
    const int t0  = blockIdx.y * TC;
    const int b   = blockIdx.x * blockDim.x + tid;

    // stage W chunk (transpose t-major -> k-major): lw[k*24+j] = W[(t0+j)*48+k]
    for (int i = tid; i < AR_P * TC; i += 256) {
        const int k = i / TC;
        const int j = i - k * TC;
        lw[i] = ws[(t0 + j) * AR_P + k];
    }
    __syncthreads();
    if (b >= B) return;

    // per-lane history: last 48 floats of row b (16B-aligned, L1/L2 line-friendly)
    float ym[AR_P];
    const float4* yp = reinterpret_cast<const float4*>(
        enc_l + (size_t)b * HISTLEN + (HISTLEN - AR_P));
#pragma unroll
    for (int i = 0; i < AR_P / 4; ++i) {
        float4 q = yp[i];
        ym[i*4+0] = q.x; ym[i*4+1] = q.y; ym[i*4+2] = q.z; ym[i*4+3] = q.w;
    }

    // acc init from ccm (wave-uniform -> s_load)
    const float* ccm = ws + AR_P * FLEN;
    float acc[TC];
#pragma unroll
    for (int j = 0; j < TC; ++j) acc[j] = ccm[t0 + j];

    // k-outer: 6 broadcast ds_read_b128 + 24 FMAs per k
#pragma unroll
    for (int k = 0; k < AR_P; ++k) {
        const float yk = ym[k];
        const float4* wr = reinterpret_cast<const float4*>(lw + k * TC);
#pragma unroll
        for (int jb = 0; jb < TC / 4; ++jb) {
            float4 w = wr[jb];
            acc[jb*4+0] = fmaf(w.x, yk, acc[jb*4+0]);
            acc[jb*4+1] = fmaf(w.y, yk, acc[jb*4+1]);
            acc[jb*4+2] = fmaf(w.z, yk, acc[jb*4+2]);
            acc[jb*4+3] = fmaf(w.w, yk, acc[jb*4+3]);
        }
    }

    // mu stores: 6 float4 per thread (96 B contiguous per thread)
    float4* dst = reinterpret_cast<float4*>(out + (size_t)b * FLEN + t0);
    const float4* av = reinterpret_cast<const float4*>(acc);
#pragma unroll
    for (int i = 0; i < TC / 4; ++i) dst[i] = av[i];

    // fused logvar fill for the same (b, t-chunk) region
    const float lv = log_sigma2[0] + 2.0f * logf(sigma_p[0]);
    const float4 v = make_float4(lv, lv, lv, lv);
    float4* dst2 = reinterpret_cast<float4*>(out + (size_t)B * FLEN + (size_t)b * FLEN + t0);
#pragma unroll
    for (int i = 0; i < TC / 4; ++i) dst2[i] = v;
}

extern "C" void kernel_launch(void* const* d_in, const int* in_sizes, int n_in,
                              void* d_out, int out_size, void* d_ws, size_t ws_size,
                              hipStream_t stream) {
    const float* enc_l = (const float*)d_in[0];
    // d_in[1..3] = enc_t, enc_w, enc_s (unused by the reference)
    const float* phi  = (const float*)d_in[4];
    const float* bias = (const float*)d_in[5];
    const float* ls2  = (const float*)d_in[6];
    const float* mu   = (const float*)d_in[7];
    const float* sg   = (const float*)d_in[8];
    float* ws  = (float*)d_ws;
    float* out = (float*)d_out;
    const int B = in_sizes[0] / HISTLEN;

    hipLaunchKernelGGL(k_coeffs, dim3(1), dim3(64), 0, stream,
                       phi, bias, mu, sg, ws);
    hipLaunchKernelGGL(k_mu, dim3((B + 255) / 256, FLEN / TC), dim3(256), 0, stream,
                       enc_l, ws, ls2, sg, out, B);
}